// Round 1
// baseline (857.707 us; speedup 1.0000x reference)
//
#include <hip/hip_runtime.h>

#define ROWLEN 16384
#define NF4 (ROWLEN / 4)   // 4096 float4 per row
#define NT 512             // threads per block
#define EPT 32             // elements per thread
#define KSEL 64u

// Order-preserving float -> u32 key (larger key == larger float, NaN-free input)
__device__ __forceinline__ unsigned f2k(float f) {
    unsigned u = __float_as_uint(f);
    return (u & 0x80000000u) ? ~u : (u | 0x80000000u);
}
__device__ __forceinline__ float k2f(unsigned k) {
    unsigned u = (k & 0x80000000u) ? (k ^ 0x80000000u) : ~k;
    return __uint_as_float(u);
}

__global__ __launch_bounds__(NT, 4)
void sparsify_topk_kernel(const float* __restrict__ x, float* __restrict__ out, int rows) {
    const int t = threadIdx.x;
    const int row = blockIdx.x;
    if (row >= rows) return;  // uniform per block

    __shared__ unsigned h0[256], h1[256];   // double-buffered histograms
    __shared__ unsigned selBin, selK;

    // ---- Load row into registers as sortable keys (coalesced float4) ----
    const float4* xrow = (const float4*)(x + (size_t)row * ROWLEN);
    unsigned keys[EPT];
#pragma unroll
    for (int j = 0; j < EPT / 4; ++j) {
        float4 v = xrow[j * NT + t];
        keys[4 * j + 0] = f2k(v.x);
        keys[4 * j + 1] = f2k(v.y);
        keys[4 * j + 2] = f2k(v.z);
        keys[4 * j + 3] = f2k(v.w);
    }

    if (t < 256) h0[t] = 0u;
    else         h1[t - 256] = 0u;
    __syncthreads();

    unsigned prefix = 0;   // key bits above current pass (block-uniform)
    unsigned kcur = KSEL;  // remaining rank within prefix (block-uniform, <= 64)

    // Radix-select pass over 8 bits at SHIFT.
    // Saturating counts (cap 64 == K). Race-tolerance proof: every atomicAdd
    // corresponds to a distinct element, so hist[b] <= true_b; a stale read can
    // only under-observe the cap, so hist[b] >= min(true_b, 64). Bins above the
    // crossing bin have true counts < kcur <= 64 => exact; the crossing bin only
    // needs >= (kcur - suffix_above), which min(true,64) guarantees. Hence the
    // 8-wide batched reads below (which break the ds_read->ds_add latency chain)
    // are safe no matter how stale they are.
#define HPASS(SHIFT, FIRST, HC, HN, ZN)                                        \
    {                                                                          \
        _Pragma("unroll")                                                      \
        for (int g = 0; g < EPT; g += 8) {                                     \
            unsigned bb[8], cc[8]; bool vl[8];                                 \
            _Pragma("unroll")                                                  \
            for (int i = 0; i < 8; ++i) {                                      \
                unsigned key = keys[g + i];                                    \
                vl[i] = (FIRST) || ((key >> ((SHIFT) + 8)) == prefix);         \
                bb[i] = (key >> (SHIFT)) & 255u;                               \
            }                                                                  \
            _Pragma("unroll")                                                  \
            for (int i = 0; i < 8; ++i) cc[i] = vl[i] ? HC[bb[i]] : KSEL;      \
            _Pragma("unroll")                                                  \
            for (int i = 0; i < 8; ++i)                                        \
                if (cc[i] < KSEL) atomicAdd(&HC[bb[i]], 1u);                   \
        }                                                                      \
        __syncthreads();                                                       \
        if (t < 64) {                                                          \
            unsigned c0 = HC[4 * t + 0], c1 = HC[4 * t + 1];                   \
            unsigned c2 = HC[4 * t + 2], c3 = HC[4 * t + 3];                   \
            unsigned s = c0 + c1 + c2 + c3;                                    \
            _Pragma("unroll")                                                  \
            for (int d = 1; d < 64; d <<= 1) {                                 \
                unsigned v = __shfl_down(s, d);                                \
                if (t + d < 64) s += v;                                        \
            }                                                                  \
            unsigned sAb = __shfl_down(s, 1);                                  \
            if (t == 63) sAb = 0;                                              \
            if (s >= kcur && sAb < kcur) { /* exactly one lane */              \
                unsigned a = sAb;                                              \
                int bin; unsigned kn;                                          \
                if (a + c3 >= kcur)                { bin = 4*t+3; kn = kcur - a; }                    \
                else if (a + c3 + c2 >= kcur)      { bin = 4*t+2; kn = kcur - a - c3; }               \
                else if (a + c3 + c2 + c1 >= kcur) { bin = 4*t+1; kn = kcur - a - c3 - c2; }          \
                else                               { bin = 4*t+0; kn = kcur - a - c3 - c2 - c1; }     \
                selBin = (unsigned)bin;                                        \
                selK = kn;                                                     \
            }                                                                  \
        } else if ((ZN) && t >= 256) {                                         \
            HN[t - 256] = 0u; /* zero next pass's histogram in parallel */     \
        }                                                                      \
        __syncthreads();                                                       \
        prefix = (prefix << 8) | selBin;                                       \
        kcur = selK;                                                           \
    }

    HPASS(24, true,  h0, h1, 1)
    HPASS(16, false, h1, h0, 1)
    HPASS(8,  false, h0, h1, 1)
    HPASS(0,  false, h1, h0, 0)
#undef HPASS

    const unsigned tkey = prefix;  // exact key of the K-th largest value

    // ---- Epilogue: mask in key space, reconstruct floats, coalesced store ----
    float4* orow = (float4*)out + (size_t)row * NF4;
#pragma unroll
    for (int j = 0; j < EPT / 4; ++j) {
        unsigned k0 = keys[4 * j + 0], k1 = keys[4 * j + 1];
        unsigned k2 = keys[4 * j + 2], k3 = keys[4 * j + 3];
        float4 o;
        o.x = (k0 >= tkey) ? k2f(k0) : 0.0f;
        o.y = (k1 >= tkey) ? k2f(k1) : 0.0f;
        o.z = (k2 >= tkey) ? k2f(k2) : 0.0f;
        o.w = (k3 >= tkey) ? k2f(k3) : 0.0f;
        orow[j * NT + t] = o;
    }
}

extern "C" void kernel_launch(void* const* d_in, const int* in_sizes, int n_in,
                              void* d_out, int out_size, void* d_ws, size_t ws_size,
                              hipStream_t stream) {
    const float* x = (const float*)d_in[0];
    float* out = (float*)d_out;
    const int rows = in_sizes[0] / ROWLEN;
    sparsify_topk_kernel<<<rows, NT, 0, stream>>>(x, out, rows);
}

// Round 2
// 841.830 us; speedup vs baseline: 1.0189x; 1.0189x over previous
//
#include <hip/hip_runtime.h>

#define ROWLEN 16384
#define NF4 (ROWLEN / 4)   // 4096 float4 per row
#define NT 1024            // threads per block (16 waves)
#define EPT 16             // elements per thread
#define KSEL 64u

// Order-preserving float -> u32 key (larger key == larger float, NaN-free input)
__device__ __forceinline__ unsigned f2k(float f) {
    unsigned u = __float_as_uint(f);
    return (u & 0x80000000u) ? ~u : (u | 0x80000000u);
}
__device__ __forceinline__ float k2f(unsigned k) {
    unsigned u = (k & 0x80000000u) ? (k ^ 0x80000000u) : ~k;
    return __uint_as_float(u);
}

// __launch_bounds__(1024, 8): 8 waves/SIMD min => VGPR cap 64 => 32 waves/CU
// = 4 blocks/CU resident. keys[16] + temps ~= 40 VGPR, fits.
__global__ __launch_bounds__(NT, 8)
void sparsify_topk_kernel(const float* __restrict__ x, float* __restrict__ out, int rows) {
    const int t = threadIdx.x;
    const int row = blockIdx.x;
    if (row >= rows) return;  // uniform per block

    __shared__ unsigned h0[256], h1[256];   // double-buffered histograms
    __shared__ unsigned selBin, selK;

    // ---- Load row into registers as sortable keys (coalesced float4) ----
    const float4* xrow = (const float4*)(x + (size_t)row * ROWLEN);
    unsigned keys[EPT];
#pragma unroll
    for (int j = 0; j < EPT / 4; ++j) {
        float4 v = xrow[j * NT + t];
        keys[4 * j + 0] = f2k(v.x);
        keys[4 * j + 1] = f2k(v.y);
        keys[4 * j + 2] = f2k(v.z);
        keys[4 * j + 3] = f2k(v.w);
    }

    if (t < 256)      h0[t] = 0u;
    else if (t < 512) h1[t - 256] = 0u;
    __syncthreads();

    unsigned prefix = 0;   // key bits above current pass (block-uniform)
    unsigned kcur = KSEL;  // remaining rank within prefix (block-uniform, <= 64)

    // Radix-select pass over 8 bits at SHIFT.
    // Saturating counts (cap 64 == K). Race-tolerance: every atomicAdd maps to
    // a distinct element so hist[b] <= true_b; a stale read only under-sees the
    // cap so hist[b] >= min(true_b, 64). Bins above the crossing bin have true
    // counts < kcur <= 64 => exact; the crossing bin only needs
    // >= (kcur - suffix_above), which min(true,64) guarantees.
#define HPASS(SHIFT, FIRST, HC, HN, ZN)                                        \
    {                                                                          \
        _Pragma("unroll")                                                      \
        for (int e = 0; e < EPT; ++e) {                                        \
            unsigned key = keys[e];                                            \
            bool valid = (FIRST) || ((key >> ((SHIFT) + 8)) == prefix);        \
            if (valid) {                                                       \
                unsigned b = (key >> (SHIFT)) & 255u;                          \
                if (HC[b] < KSEL) atomicAdd(&HC[b], 1u);                       \
            }                                                                  \
        }                                                                      \
        __syncthreads();                                                       \
        if (t < 64) {                                                          \
            unsigned c0 = HC[4 * t + 0], c1 = HC[4 * t + 1];                   \
            unsigned c2 = HC[4 * t + 2], c3 = HC[4 * t + 3];                   \
            unsigned s = c0 + c1 + c2 + c3;                                    \
            _Pragma("unroll")                                                  \
            for (int d = 1; d < 64; d <<= 1) {                                 \
                unsigned v = __shfl_down(s, d);                                \
                if (t + d < 64) s += v;                                        \
            }                                                                  \
            unsigned sAb = __shfl_down(s, 1);                                  \
            if (t == 63) sAb = 0;                                              \
            if (s >= kcur && sAb < kcur) { /* exactly one lane */              \
                unsigned a = sAb;                                              \
                int bin; unsigned kn;                                          \
                if (a + c3 >= kcur)                { bin = 4*t+3; kn = kcur - a; }                    \
                else if (a + c3 + c2 >= kcur)      { bin = 4*t+2; kn = kcur - a - c3; }               \
                else if (a + c3 + c2 + c1 >= kcur) { bin = 4*t+1; kn = kcur - a - c3 - c2; }          \
                else                               { bin = 4*t+0; kn = kcur - a - c3 - c2 - c1; }     \
                selBin = (unsigned)bin;                                        \
                selK = kn;                                                     \
            }                                                                  \
        } else if ((ZN) && t >= 512 && t < 768) {                              \
            HN[t - 512] = 0u; /* zero next pass's histogram in parallel */     \
        }                                                                      \
        __syncthreads();                                                       \
        prefix = (prefix << 8) | selBin;                                       \
        kcur = selK;                                                           \
    }

    HPASS(24, true,  h0, h1, 1)
    HPASS(16, false, h1, h0, 1)
    HPASS(8,  false, h0, h1, 1)
    HPASS(0,  false, h1, h0, 0)
#undef HPASS

    const unsigned tkey = prefix;  // exact key of the K-th largest value

    // ---- Epilogue: mask in key space, reconstruct floats, coalesced store ----
    float4* orow = (float4*)out + (size_t)row * NF4;
#pragma unroll
    for (int j = 0; j < EPT / 4; ++j) {
        unsigned k0 = keys[4 * j + 0], k1 = keys[4 * j + 1];
        unsigned k2 = keys[4 * j + 2], k3 = keys[4 * j + 3];
        float4 o;
        o.x = (k0 >= tkey) ? k2f(k0) : 0.0f;
        o.y = (k1 >= tkey) ? k2f(k1) : 0.0f;
        o.z = (k2 >= tkey) ? k2f(k2) : 0.0f;
        o.w = (k3 >= tkey) ? k2f(k3) : 0.0f;
        orow[j * NT + t] = o;
    }
}

extern "C" void kernel_launch(void* const* d_in, const int* in_sizes, int n_in,
                              void* d_out, int out_size, void* d_ws, size_t ws_size,
                              hipStream_t stream) {
    const float* x = (const float*)d_in[0];
    float* out = (float*)d_out;
    const int rows = in_sizes[0] / ROWLEN;
    sparsify_topk_kernel<<<rows, NT, 0, stream>>>(x, out, rows);
}